// Round 1
// baseline (1142.354 us; speedup 1.0000x reference)
//
#include <hip/hip_runtime.h>

#define DD 128

// h = x @ W.T + b  — W cached in LDS (padded to 129 to kill bank conflicts),
// 256 threads = 2 rows per iteration, thread j computes h[row][j].
__global__ __launch_bounds__(256) void gemm_h(const float* __restrict__ x,
    const float* __restrict__ W, const float* __restrict__ bias,
    float* __restrict__ h, int N) {
  __shared__ float Ws[DD][DD + 1];
  __shared__ float xs[2][DD];
  for (int i = threadIdx.x; i < DD * DD; i += 256) {
    Ws[i >> 7][i & 127] = W[i];
  }
  const int half = threadIdx.x >> 7;   // 0 or 1
  const int j    = threadIdx.x & 127;  // output column
  const float bj = bias[j];
  __syncthreads();
  for (int row0 = blockIdx.x * 2; row0 < N; row0 += gridDim.x * 2) {
    const int row = row0 + half;
    if (row < N) xs[half][j] = x[row * DD + j];
    __syncthreads();
    if (row < N) {
      float acc = bj;
      #pragma unroll
      for (int k = 0; k < DD; ++k) acc = fmaf(xs[half][k], Ws[j][k], acc);
      h[row * DD + j] = acc;
    }
    __syncthreads();
  }
}

// in-degree count via int atomics
__global__ void count_deg(const int* __restrict__ dst, int* __restrict__ cnt, int E) {
  int i = blockIdx.x * blockDim.x + threadIdx.x;
  if (i < E) atomicAdd(cnt + dst[i], 1);
}

// dis[i] = rsqrt(deg); out[i] = relu(h[i]+root)/deg   (writes EVERY out element)
__global__ void selfloop_kernel(const float* __restrict__ h, const int* __restrict__ cnt,
    const float* __restrict__ root, float* __restrict__ out,
    float* __restrict__ dis, int N) {
  int gid = blockIdx.x * blockDim.x + threadIdx.x;
  if (gid >= N * 32) return;
  const int i = gid >> 5, q = gid & 31;
  const float deg = (float)(cnt[i] + 1);
  const float inv = 1.0f / deg;
  if (q == 0) dis[i] = rsqrtf(deg);
  const float4 hv = reinterpret_cast<const float4*>(h)[gid];
  const float4 rv = reinterpret_cast<const float4*>(root)[q];
  float4 o;
  o.x = fmaxf(hv.x + rv.x, 0.0f) * inv;
  o.y = fmaxf(hv.y + rv.y, 0.0f) * inv;
  o.z = fmaxf(hv.z + rv.z, 0.0f) * inv;
  o.w = fmaxf(hv.w + rv.w, 0.0f) * inv;
  reinterpret_cast<float4*>(out)[gid] = o;
}

// per (edge, 4 floats): gather float4 of h[src], relu*norm, 4 atomicAdds to out[dst]
__global__ void edge_agg(const int* __restrict__ src, const int* __restrict__ dst,
    const float* __restrict__ h, const float* __restrict__ dis,
    float* __restrict__ out, int E) {
  int gid = blockIdx.x * blockDim.x + threadIdx.x;
  if (gid >= E * 32) return;
  const int e = gid >> 5, q = gid & 31;
  const int s = src[e], t = dst[e];
  const float norm = dis[s] * dis[t];
  const float4 hv = reinterpret_cast<const float4*>(h)[s * 32 + q];
  float* op = out + t * DD + q * 4;
  atomicAdd(op + 0, fmaxf(hv.x, 0.0f) * norm);
  atomicAdd(op + 1, fmaxf(hv.y, 0.0f) * norm);
  atomicAdd(op + 2, fmaxf(hv.z, 0.0f) * norm);
  atomicAdd(op + 3, fmaxf(hv.w, 0.0f) * norm);
}

extern "C" void kernel_launch(void* const* d_in, const int* in_sizes, int n_in,
                              void* d_out, int out_size, void* d_ws, size_t ws_size,
                              hipStream_t stream) {
  const float* x    = (const float*)d_in[0];
  const int*   src  = (const int*)d_in[1];
  const int*   dst  = (const int*)d_in[2];
  const float* W    = (const float*)d_in[3];
  const float* bias = (const float*)d_in[4];
  const float* root = (const float*)d_in[5];
  float* out = (float*)d_out;
  const int N = in_sizes[0] / DD;
  const int E = in_sizes[1];

  char* ws   = (char*)d_ws;
  float* h   = (float*)ws;                                   // N*DD floats
  int*   cnt = (int*)(ws + (size_t)N * DD * 4);              // N ints
  float* dis = (float*)(ws + (size_t)N * DD * 4 + (size_t)N * 4);  // N floats

  hipMemsetAsync(cnt, 0, (size_t)N * 4, stream);
  gemm_h<<<2048, 256, 0, stream>>>(x, W, bias, h, N);
  count_deg<<<(E + 255) / 256, 256, 0, stream>>>(dst, cnt, E);
  selfloop_kernel<<<(N * 32 + 255) / 256, 256, 0, stream>>>(h, cnt, root, out, dis, N);
  edge_agg<<<((E * 32) + 255) / 256, 256, 0, stream>>>(src, dst, h, dis, out, E);
}

// Round 2
// 306.444 us; speedup vs baseline: 3.7278x; 3.7278x over previous
//
#include <hip/hip_runtime.h>

#define DD 128

// h = x @ W.T + b  — W cached in LDS (padded), 2 rows per block-iteration.
__global__ __launch_bounds__(256) void gemm_h(const float* __restrict__ x,
    const float* __restrict__ W, const float* __restrict__ bias,
    float* __restrict__ h, int N) {
  __shared__ float Ws[DD][DD + 1];
  __shared__ float xs[2][DD];
  for (int i = threadIdx.x; i < DD * DD; i += 256) {
    Ws[i >> 7][i & 127] = W[i];
  }
  const int half = threadIdx.x >> 7;   // 0 or 1
  const int j    = threadIdx.x & 127;  // output column
  const float bj = bias[j];
  __syncthreads();
  for (int row0 = blockIdx.x * 2; row0 < N; row0 += gridDim.x * 2) {
    const int row = row0 + half;
    if (row < N) xs[half][j] = x[row * DD + j];
    __syncthreads();
    if (row < N) {
      float acc = bj;
      #pragma unroll
      for (int k = 0; k < DD; ++k) acc = fmaf(xs[half][k], Ws[j][k], acc);
      h[row * DD + j] = acc;
    }
    __syncthreads();
  }
}

// in-degree count via int atomics
__global__ void count_deg(const int* __restrict__ dst, int* __restrict__ cnt, int E) {
  int i = blockIdx.x * blockDim.x + threadIdx.x;
  if (i < E) atomicAdd(cnt + dst[i], 1);
}

// dis[i] = rsqrt(deg_i), deg = cnt+1
__global__ void compute_dis(const int* __restrict__ cnt, float* __restrict__ dis, int N) {
  int i = blockIdx.x * blockDim.x + threadIdx.x;
  if (i < N) dis[i] = rsqrtf((float)(cnt[i] + 1));
}

// single-block exclusive scan: rowptr[i] = sum(cnt[0..i-1]), rowptr[N] = E
__global__ __launch_bounds__(1024) void scan_kernel(const int* __restrict__ cnt,
    int* __restrict__ rowptr, int N) {
  __shared__ int buf[1024];
  __shared__ int carry_s;
  const int tid = threadIdx.x;
  if (tid == 0) carry_s = 0;
  for (int base = 0; base < N; base += 1024) {
    const int idx = base + tid;
    const int v = (idx < N) ? cnt[idx] : 0;
    __syncthreads();              // carry_s from prev iter visible; buf free
    buf[tid] = v;
    __syncthreads();
    for (int off = 1; off < 1024; off <<= 1) {
      int t = (tid >= off) ? buf[tid - off] : 0;
      __syncthreads();
      buf[tid] += t;
      __syncthreads();
    }
    const int c = carry_s;
    if (idx < N) rowptr[idx] = c + buf[tid] - v;   // exclusive
    __syncthreads();
    if (tid == 0) carry_s = c + buf[1023];
  }
  __syncthreads();
  if (tid == 0) rowptr[N] = carry_s;
}

// scatter edges into dst-grouped order: esrc[rowptr[dst]+k] = src
__global__ void fill_csr(const int* __restrict__ src, const int* __restrict__ dst,
    const int* __restrict__ rowptr, int* __restrict__ cursor,
    int* __restrict__ esrc, int E) {
  int e = blockIdx.x * blockDim.x + threadIdx.x;
  if (e < E) {
    const int t = dst[e];
    const int p = rowptr[t] + atomicAdd(cursor + t, 1);
    esrc[p] = src[e];
  }
}

// per node: 32 threads each own a float4 column slice; loop in-edges, no atomics.
// out[n] = sum_{e in N(n)} relu(h[src])*dis[src]*dis[n]  +  relu(h[n]+root)/deg
__global__ __launch_bounds__(256) void csr_agg(const int* __restrict__ esrc,
    const int* __restrict__ rowptr, const float* __restrict__ h,
    const float* __restrict__ dis, const float* __restrict__ root,
    float* __restrict__ out, int N) {
  int gid = blockIdx.x * blockDim.x + threadIdx.x;
  if (gid >= N * 32) return;
  const int n = gid >> 5, q = gid & 31;
  const float dt  = dis[n];
  const float inv = dt * dt;            // 1/deg
  const float4* h4 = reinterpret_cast<const float4*>(h);
  const float4 rv = reinterpret_cast<const float4*>(root)[q];
  const float4 hv = h4[n * 32 + q];
  float4 acc;
  acc.x = fmaxf(hv.x + rv.x, 0.0f) * inv;
  acc.y = fmaxf(hv.y + rv.y, 0.0f) * inv;
  acc.z = fmaxf(hv.z + rv.z, 0.0f) * inv;
  acc.w = fmaxf(hv.w + rv.w, 0.0f) * inv;
  const int beg = rowptr[n], end = rowptr[n + 1];
  for (int k = beg; k < end; ++k) {
    const int s = esrc[k];
    const float w = dis[s] * dt;
    const float4 v = h4[s * 32 + q];
    acc.x += fmaxf(v.x, 0.0f) * w;
    acc.y += fmaxf(v.y, 0.0f) * w;
    acc.z += fmaxf(v.z, 0.0f) * w;
    acc.w += fmaxf(v.w, 0.0f) * w;
  }
  reinterpret_cast<float4*>(out)[gid] = acc;
}

extern "C" void kernel_launch(void* const* d_in, const int* in_sizes, int n_in,
                              void* d_out, int out_size, void* d_ws, size_t ws_size,
                              hipStream_t stream) {
  const float* x    = (const float*)d_in[0];
  const int*   src  = (const int*)d_in[1];
  const int*   dst  = (const int*)d_in[2];
  const float* W    = (const float*)d_in[3];
  const float* bias = (const float*)d_in[4];
  const float* root = (const float*)d_in[5];
  float* out = (float*)d_out;
  const int N = in_sizes[0] / DD;
  const int E = in_sizes[1];

  char* ws = (char*)d_ws;
  size_t off = 0;
  float* h      = (float*)(ws + off); off += (size_t)N * DD * 4;
  int*   cnt    = (int*)  (ws + off); off += (size_t)N * 4;
  float* dis    = (float*)(ws + off); off += (size_t)N * 4;
  int*   rowptr = (int*)  (ws + off); off += (size_t)(N + 1) * 4;
  int*   cursor = (int*)  (ws + off); off += (size_t)N * 4;
  int*   esrc   = (int*)  (ws + off); off += (size_t)E * 4;

  hipMemsetAsync(cnt, 0, (size_t)N * 4, stream);
  hipMemsetAsync(cursor, 0, (size_t)N * 4, stream);
  gemm_h<<<2048, 256, 0, stream>>>(x, W, bias, h, N);
  count_deg<<<(E + 255) / 256, 256, 0, stream>>>(dst, cnt, E);
  compute_dis<<<(N + 255) / 256, 256, 0, stream>>>(cnt, dis, N);
  scan_kernel<<<1, 1024, 0, stream>>>(cnt, rowptr, N);
  fill_csr<<<(E + 255) / 256, 256, 0, stream>>>(src, dst, rowptr, cursor, esrc, E);
  csr_agg<<<(N * 32 + 255) / 256, 256, 0, stream>>>(esrc, rowptr, h, dis, root, out, N);
}

// Round 3
// 156.518 us; speedup vs baseline: 7.2985x; 1.9579x over previous
//
#include <hip/hip_runtime.h>

#define DD 128

typedef _Float16 h8 __attribute__((ext_vector_type(8)));
typedef float f4 __attribute__((ext_vector_type(4)));

// W (fp32, [j][k]) -> Wh (fp16, same layout). B[k][j] = W[j][k], so a B-fragment
// (8 contiguous k for fixed j) is 8 contiguous halfs here.
__global__ void wconv(const float* __restrict__ W, _Float16* __restrict__ Wh) {
  int i = blockIdx.x * blockDim.x + threadIdx.x;
  if (i < DD * DD) Wh[i] = (_Float16)W[i];
}

// h = x @ W.T + b via 16x16x32 f16 MFMA. Whole W lives in each wave's registers
// (8 col-tiles x 4 k-steps x 4 VGPR = 128 VGPR), so zero LDS and A comes straight
// from global with inline fp32->fp16 cvt. Wave processes 16-row tiles, grid-stride.
__global__ __launch_bounds__(256, 2) void gemm_mfma(const float* __restrict__ x,
    const _Float16* __restrict__ Wh, const float* __restrict__ bias,
    float* __restrict__ h, int nrt) {
  const int lane = threadIdx.x & 63;
  const int wid  = blockIdx.x * 4 + (threadIdx.x >> 6);
  const int nw   = gridDim.x * 4;
  const int lrow = lane & 15;          // A row / B col / C col
  const int lk   = (lane >> 4) << 3;   // k base within 32-wide k-step
  h8 wb[8][4];
#pragma unroll
  for (int jt = 0; jt < 8; ++jt)
#pragma unroll
    for (int ks = 0; ks < 4; ++ks)
      wb[jt][ks] = *(const h8*)(Wh + (jt * 16 + lrow) * DD + ks * 32 + lk);
  float bj[8];
#pragma unroll
  for (int jt = 0; jt < 8; ++jt) bj[jt] = bias[jt * 16 + lrow];
  const int srow = (lane >> 4) << 2;   // C row base = (lane>>4)*4 + reg
  for (int rt = wid; rt < nrt; rt += nw) {
    const int row0 = rt * 16;
    f4 acc[8];
#pragma unroll
    for (int jt = 0; jt < 8; ++jt) acc[jt] = (f4){0.f, 0.f, 0.f, 0.f};
#pragma unroll
    for (int ks = 0; ks < 4; ++ks) {
      const float* ap = x + (size_t)(row0 + lrow) * DD + ks * 32 + lk;
      const f4 a0 = *(const f4*)ap;
      const f4 a1 = *(const f4*)(ap + 4);
      h8 af;
      af[0] = (_Float16)a0.x; af[1] = (_Float16)a0.y;
      af[2] = (_Float16)a0.z; af[3] = (_Float16)a0.w;
      af[4] = (_Float16)a1.x; af[5] = (_Float16)a1.y;
      af[6] = (_Float16)a1.z; af[7] = (_Float16)a1.w;
#pragma unroll
      for (int jt = 0; jt < 8; ++jt)
        acc[jt] = __builtin_amdgcn_mfma_f32_16x16x32_f16(af, wb[jt][ks], acc[jt], 0, 0, 0);
    }
    float* hp = h + (size_t)(row0 + srow) * DD + lrow;
#pragma unroll
    for (int jt = 0; jt < 8; ++jt)
#pragma unroll
      for (int r = 0; r < 4; ++r)
        hp[(size_t)r * DD + jt * 16] = acc[jt][r] + bj[jt];
  }
}

__global__ void count_deg(const int* __restrict__ dst, int* __restrict__ cnt, int E) {
  int i = blockIdx.x * blockDim.x + threadIdx.x;
  if (i < E) atomicAdd(cnt + dst[i], 1);
}

__global__ void compute_dis(const int* __restrict__ cnt, float* __restrict__ dis, int N) {
  int i = blockIdx.x * blockDim.x + threadIdx.x;
  if (i < N) dis[i] = rsqrtf((float)(cnt[i] + 1));
}

// two-level exclusive scan: scan1 (1024 elems/block) -> scan2 (block sums) -> scan3 (add)
__global__ __launch_bounds__(256) void scan1(const int* __restrict__ cnt,
    int* __restrict__ rowptr, int* __restrict__ bsum, int N) {
  __shared__ int s[256];
  const int tid = threadIdx.x;
  const int idx = blockIdx.x * 1024 + tid * 4;
  int4 v = {0, 0, 0, 0};
  if (idx + 3 < N) v = *(const int4*)(cnt + idx);
  else {
    if (idx + 0 < N) v.x = cnt[idx];
    if (idx + 1 < N) v.y = cnt[idx + 1];
    if (idx + 2 < N) v.z = cnt[idx + 2];
  }
  const int mysum = v.x + v.y + v.z + v.w;
  s[tid] = mysum;
  __syncthreads();
  for (int off = 1; off < 256; off <<= 1) {
    int t = (tid >= off) ? s[tid - off] : 0;
    __syncthreads();
    s[tid] += t;
    __syncthreads();
  }
  if (tid == 255) bsum[blockIdx.x] = s[255];
  int p = s[tid] - mysum;
  if (idx + 0 < N) rowptr[idx + 0] = p; p += v.x;
  if (idx + 1 < N) rowptr[idx + 1] = p; p += v.y;
  if (idx + 2 < N) rowptr[idx + 2] = p; p += v.z;
  if (idx + 3 < N) rowptr[idx + 3] = p;
}

__global__ __launch_bounds__(256) void scan2(const int* __restrict__ bsum,
    int* __restrict__ boff, int* __restrict__ rowptr, int nb, int N) {
  __shared__ int s[256];
  const int tid = threadIdx.x;
  const int v = (tid < nb) ? bsum[tid] : 0;
  s[tid] = v;
  __syncthreads();
  for (int off = 1; off < 256; off <<= 1) {
    int t = (tid >= off) ? s[tid - off] : 0;
    __syncthreads();
    s[tid] += t;
    __syncthreads();
  }
  if (tid < nb) boff[tid] = s[tid] - v;
  if (tid == 255) rowptr[N] = s[255];
}

__global__ void scan3(int* __restrict__ rowptr, const int* __restrict__ boff, int N) {
  int i = blockIdx.x * blockDim.x + threadIdx.x;
  if (i < N) rowptr[i] += boff[i >> 10];
}

__global__ void fill_csr(const int* __restrict__ src, const int* __restrict__ dst,
    const int* __restrict__ rowptr, int* __restrict__ cursor,
    int* __restrict__ esrc, int E) {
  int e = blockIdx.x * blockDim.x + threadIdx.x;
  if (e < E) {
    const int t = dst[e];
    const int p = rowptr[t] + atomicAdd(cursor + t, 1);
    esrc[p] = src[e];
  }
}

// per node: 32 threads each own a float4 column slice; loop in-edges, no atomics.
__global__ __launch_bounds__(256) void csr_agg(const int* __restrict__ esrc,
    const int* __restrict__ rowptr, const float* __restrict__ h,
    const float* __restrict__ dis, const float* __restrict__ root,
    float* __restrict__ out, int N) {
  int gid = blockIdx.x * blockDim.x + threadIdx.x;
  if (gid >= N * 32) return;
  const int n = gid >> 5, q = gid & 31;
  const float dt  = dis[n];
  const float inv = dt * dt;            // 1/deg
  const float4* h4 = reinterpret_cast<const float4*>(h);
  const float4 rv = reinterpret_cast<const float4*>(root)[q];
  const float4 hv = h4[n * 32 + q];
  float4 acc;
  acc.x = fmaxf(hv.x + rv.x, 0.0f) * inv;
  acc.y = fmaxf(hv.y + rv.y, 0.0f) * inv;
  acc.z = fmaxf(hv.z + rv.z, 0.0f) * inv;
  acc.w = fmaxf(hv.w + rv.w, 0.0f) * inv;
  const int beg = rowptr[n], end = rowptr[n + 1];
  for (int k = beg; k < end; ++k) {
    const int s = esrc[k];
    const float w = dis[s] * dt;
    const float4 v = h4[s * 32 + q];
    acc.x += fmaxf(v.x, 0.0f) * w;
    acc.y += fmaxf(v.y, 0.0f) * w;
    acc.z += fmaxf(v.z, 0.0f) * w;
    acc.w += fmaxf(v.w, 0.0f) * w;
  }
  reinterpret_cast<float4*>(out)[gid] = acc;
}

extern "C" void kernel_launch(void* const* d_in, const int* in_sizes, int n_in,
                              void* d_out, int out_size, void* d_ws, size_t ws_size,
                              hipStream_t stream) {
  const float* x    = (const float*)d_in[0];
  const int*   src  = (const int*)d_in[1];
  const int*   dst  = (const int*)d_in[2];
  const float* W    = (const float*)d_in[3];
  const float* bias = (const float*)d_in[4];
  const float* root = (const float*)d_in[5];
  float* out = (float*)d_out;
  const int N = in_sizes[0] / DD;
  const int E = in_sizes[1];

  char* ws = (char*)d_ws;
  size_t off = 0;
  float* h      = (float*)(ws + off); off += (size_t)N * DD * 4;
  int*   cnt    = (int*)  (ws + off); off += (size_t)N * 4;
  float* dis    = (float*)(ws + off); off += (size_t)N * 4;
  int*   rowptr = (int*)  (ws + off); off += (size_t)(N + 2) * 4;
  int*   cursor = (int*)  (ws + off); off += (size_t)N * 4;
  int*   esrc   = (int*)  (ws + off); off += (size_t)E * 4;
  int*   bsum   = (int*)  (ws + off); off += 256 * 4;
  int*   boff   = (int*)  (ws + off); off += 256 * 4;
  _Float16* Wh  = (_Float16*)(ws + off); off += (size_t)DD * DD * 2;

  const int nb = (N + 1023) / 1024;  // 49
  hipMemsetAsync(cnt, 0, (size_t)N * 4, stream);
  hipMemsetAsync(cursor, 0, (size_t)N * 4, stream);
  wconv<<<(DD * DD + 255) / 256, 256, 0, stream>>>(W, Wh);
  gemm_mfma<<<391, 256, 0, stream>>>(x, Wh, bias, h, N / 16);
  count_deg<<<(E + 255) / 256, 256, 0, stream>>>(dst, cnt, E);
  compute_dis<<<(N + 255) / 256, 256, 0, stream>>>(cnt, dis, N);
  scan1<<<nb, 256, 0, stream>>>(cnt, rowptr, bsum, N);
  scan2<<<1, 256, 0, stream>>>(bsum, boff, rowptr, nb, N);
  scan3<<<(N + 255) / 256, 256, 0, stream>>>(rowptr, boff, N);
  fill_csr<<<(E + 255) / 256, 256, 0, stream>>>(src, dst, rowptr, cursor, esrc, E);
  csr_agg<<<(N * 32 + 255) / 256, 256, 0, stream>>>(esrc, rowptr, h, dis, root, out, N);
}

// Round 4
// 127.576 us; speedup vs baseline: 8.9543x; 1.2269x over previous
//
#include <hip/hip_runtime.h>

#define DD 128

typedef _Float16 h8 __attribute__((ext_vector_type(8)));
typedef _Float16 h4v __attribute__((ext_vector_type(4)));
typedef float f4 __attribute__((ext_vector_type(4)));

// W (fp32, [j][k]) -> Wh (fp16, same layout).
__global__ void wconv(const float* __restrict__ W, _Float16* __restrict__ Wh) {
  int i = blockIdx.x * blockDim.x + threadIdx.x;
  if (i < DD * DD) Wh[i] = (_Float16)W[i];
}

// h16 = fp16(x @ W.T + b) via 16x16x32 f16 MFMA; whole W in wave registers, no LDS.
__global__ __launch_bounds__(256, 2) void gemm_mfma(const float* __restrict__ x,
    const _Float16* __restrict__ Wh, const float* __restrict__ bias,
    _Float16* __restrict__ h16, int nrt) {
  const int lane = threadIdx.x & 63;
  const int wid  = blockIdx.x * 4 + (threadIdx.x >> 6);
  const int nw   = gridDim.x * 4;
  const int lrow = lane & 15;          // A row / B col / C col
  const int lk   = (lane >> 4) << 3;   // k base within 32-wide k-step
  h8 wb[8][4];
#pragma unroll
  for (int jt = 0; jt < 8; ++jt)
#pragma unroll
    for (int ks = 0; ks < 4; ++ks)
      wb[jt][ks] = *(const h8*)(Wh + (jt * 16 + lrow) * DD + ks * 32 + lk);
  float bj[8];
#pragma unroll
  for (int jt = 0; jt < 8; ++jt) bj[jt] = bias[jt * 16 + lrow];
  const int srow = (lane >> 4) << 2;   // C row base = (lane>>4)*4 + reg
  for (int rt = wid; rt < nrt; rt += nw) {
    const int row0 = rt * 16;
    f4 acc[8];
#pragma unroll
    for (int jt = 0; jt < 8; ++jt) acc[jt] = (f4){0.f, 0.f, 0.f, 0.f};
#pragma unroll
    for (int ks = 0; ks < 4; ++ks) {
      const float* ap = x + (size_t)(row0 + lrow) * DD + ks * 32 + lk;
      const f4 a0 = *(const f4*)ap;
      const f4 a1 = *(const f4*)(ap + 4);
      h8 af;
      af[0] = (_Float16)a0.x; af[1] = (_Float16)a0.y;
      af[2] = (_Float16)a0.z; af[3] = (_Float16)a0.w;
      af[4] = (_Float16)a1.x; af[5] = (_Float16)a1.y;
      af[6] = (_Float16)a1.z; af[7] = (_Float16)a1.w;
#pragma unroll
      for (int jt = 0; jt < 8; ++jt)
        acc[jt] = __builtin_amdgcn_mfma_f32_16x16x32_f16(af, wb[jt][ks], acc[jt], 0, 0, 0);
    }
    _Float16* hp = h16 + (size_t)(row0 + srow) * DD + lrow;
#pragma unroll
    for (int jt = 0; jt < 8; ++jt)
#pragma unroll
      for (int r = 0; r < 4; ++r)
        hp[(size_t)r * DD + jt * 16] = (_Float16)(acc[jt][r] + bj[jt]);
  }
}

__global__ void count_deg(const int* __restrict__ dst, int* __restrict__ cnt, int E) {
  int i = blockIdx.x * blockDim.x + threadIdx.x;
  if (i < E) atomicAdd(cnt + dst[i], 1);
}

// two-level exclusive scan; scan1 also emits dis[i] = rsqrt(cnt[i]+1)
__global__ __launch_bounds__(256) void scan1(const int* __restrict__ cnt,
    int* __restrict__ rowptr, int* __restrict__ bsum, float* __restrict__ dis, int N) {
  __shared__ int s[256];
  const int tid = threadIdx.x;
  const int idx = blockIdx.x * 1024 + tid * 4;
  int4 v = {0, 0, 0, 0};
  if (idx + 3 < N) v = *(const int4*)(cnt + idx);
  else {
    if (idx + 0 < N) v.x = cnt[idx];
    if (idx + 1 < N) v.y = cnt[idx + 1];
    if (idx + 2 < N) v.z = cnt[idx + 2];
  }
  if (idx + 0 < N) dis[idx + 0] = rsqrtf((float)(v.x + 1));
  if (idx + 1 < N) dis[idx + 1] = rsqrtf((float)(v.y + 1));
  if (idx + 2 < N) dis[idx + 2] = rsqrtf((float)(v.z + 1));
  if (idx + 3 < N) dis[idx + 3] = rsqrtf((float)(v.w + 1));
  const int mysum = v.x + v.y + v.z + v.w;
  s[tid] = mysum;
  __syncthreads();
  for (int off = 1; off < 256; off <<= 1) {
    int t = (tid >= off) ? s[tid - off] : 0;
    __syncthreads();
    s[tid] += t;
    __syncthreads();
  }
  if (tid == 255) bsum[blockIdx.x] = s[255];
  int p = s[tid] - mysum;
  if (idx + 0 < N) rowptr[idx + 0] = p; p += v.x;
  if (idx + 1 < N) rowptr[idx + 1] = p; p += v.y;
  if (idx + 2 < N) rowptr[idx + 2] = p; p += v.z;
  if (idx + 3 < N) rowptr[idx + 3] = p;
}

__global__ __launch_bounds__(256) void scan2(const int* __restrict__ bsum,
    int* __restrict__ boff, int* __restrict__ rowptr, int nb, int N) {
  __shared__ int s[256];
  const int tid = threadIdx.x;
  const int v = (tid < nb) ? bsum[tid] : 0;
  s[tid] = v;
  __syncthreads();
  for (int off = 1; off < 256; off <<= 1) {
    int t = (tid >= off) ? s[tid - off] : 0;
    __syncthreads();
    s[tid] += t;
    __syncthreads();
  }
  if (tid < nb) boff[tid] = s[tid] - v;
  if (tid == 255) rowptr[N] = s[255];
}

__global__ void scan3(int* __restrict__ rowptr, const int* __restrict__ boff, int N) {
  int i = blockIdx.x * blockDim.x + threadIdx.x;
  if (i < N) rowptr[i] += boff[i >> 10];
}

// scatter edges into dst-grouped order; cnt doubles as a decrementing cursor
// (slots deg-1..0 — any in-bucket permutation is fine).
__global__ void fill_csr(const int* __restrict__ src, const int* __restrict__ dst,
    const int* __restrict__ rowptr, int* __restrict__ cnt,
    int* __restrict__ esrc, int E) {
  int e = blockIdx.x * blockDim.x + threadIdx.x;
  if (e < E) {
    const int t = dst[e];
    const int p = rowptr[t] + atomicAdd(cnt + t, -1) - 1;
    esrc[p] = src[e];
  }
}

// per node: 32 threads each own 4 columns (8B fp16 gather); unroll-2 edge loop.
// out[n] = relu(h16[n]+root)/deg + dis[n] * sum_e relu(h16[src_e])*dis[src_e]
__global__ __launch_bounds__(256) void csr_agg(const int* __restrict__ esrc,
    const int* __restrict__ rowptr, const _Float16* __restrict__ h16,
    const float* __restrict__ dis, const float* __restrict__ root,
    float* __restrict__ out, int N) {
  int gid = blockIdx.x * blockDim.x + threadIdx.x;
  if (gid >= N * 32) return;
  const int n = gid >> 5, q = gid & 31;
  const float dt  = dis[n];
  const float inv = dt * dt;            // 1/deg
  const h4v* hv4 = reinterpret_cast<const h4v*>(h16);
  const float4 rv = reinterpret_cast<const float4*>(root)[q];
  const h4v hv = hv4[n * 32 + q];
  float4 acc;
  acc.x = fmaxf((float)hv[0] + rv.x, 0.0f) * inv;
  acc.y = fmaxf((float)hv[1] + rv.y, 0.0f) * inv;
  acc.z = fmaxf((float)hv[2] + rv.z, 0.0f) * inv;
  acc.w = fmaxf((float)hv[3] + rv.w, 0.0f) * inv;
  float4 ea = {0.f, 0.f, 0.f, 0.f};
  const int beg = rowptr[n], end = rowptr[n + 1];
  int k = beg;
  for (; k + 1 < end; k += 2) {
    const int s0 = esrc[k], s1 = esrc[k + 1];
    const float w0 = dis[s0], w1 = dis[s1];
    const h4v g0 = hv4[s0 * 32 + q];
    const h4v g1 = hv4[s1 * 32 + q];
    ea.x += fmaxf((float)g0[0], 0.0f) * w0;
    ea.y += fmaxf((float)g0[1], 0.0f) * w0;
    ea.z += fmaxf((float)g0[2], 0.0f) * w0;
    ea.w += fmaxf((float)g0[3], 0.0f) * w0;
    ea.x += fmaxf((float)g1[0], 0.0f) * w1;
    ea.y += fmaxf((float)g1[1], 0.0f) * w1;
    ea.z += fmaxf((float)g1[2], 0.0f) * w1;
    ea.w += fmaxf((float)g1[3], 0.0f) * w1;
  }
  if (k < end) {
    const int s0 = esrc[k];
    const float w0 = dis[s0];
    const h4v g0 = hv4[s0 * 32 + q];
    ea.x += fmaxf((float)g0[0], 0.0f) * w0;
    ea.y += fmaxf((float)g0[1], 0.0f) * w0;
    ea.z += fmaxf((float)g0[2], 0.0f) * w0;
    ea.w += fmaxf((float)g0[3], 0.0f) * w0;
  }
  acc.x += ea.x * dt;
  acc.y += ea.y * dt;
  acc.z += ea.z * dt;
  acc.w += ea.w * dt;
  reinterpret_cast<float4*>(out)[gid] = acc;
}

extern "C" void kernel_launch(void* const* d_in, const int* in_sizes, int n_in,
                              void* d_out, int out_size, void* d_ws, size_t ws_size,
                              hipStream_t stream) {
  const float* x    = (const float*)d_in[0];
  const int*   src  = (const int*)d_in[1];
  const int*   dst  = (const int*)d_in[2];
  const float* W    = (const float*)d_in[3];
  const float* bias = (const float*)d_in[4];
  const float* root = (const float*)d_in[5];
  float* out = (float*)d_out;
  const int N = in_sizes[0] / DD;
  const int E = in_sizes[1];

  char* ws = (char*)d_ws;
  size_t off = 0;
  _Float16* h16 = (_Float16*)(ws + off); off += (size_t)N * DD * 2;
  int*   cnt    = (int*)  (ws + off); off += (size_t)N * 4;
  float* dis    = (float*)(ws + off); off += (size_t)N * 4;
  int*   rowptr = (int*)  (ws + off); off += (size_t)(N + 2) * 4;
  int*   esrc   = (int*)  (ws + off); off += (size_t)E * 4;
  int*   bsum   = (int*)  (ws + off); off += 256 * 4;
  int*   boff   = (int*)  (ws + off); off += 256 * 4;
  _Float16* Wh  = (_Float16*)(ws + off); off += (size_t)DD * DD * 2;

  const int nb = (N + 1023) / 1024;  // 49
  hipMemsetAsync(cnt, 0, (size_t)N * 4, stream);
  wconv<<<(DD * DD + 255) / 256, 256, 0, stream>>>(W, Wh);
  gemm_mfma<<<391, 256, 0, stream>>>(x, Wh, bias, h16, N / 16);
  count_deg<<<(E + 255) / 256, 256, 0, stream>>>(dst, cnt, E);
  scan1<<<nb, 256, 0, stream>>>(cnt, rowptr, bsum, dis, N);
  scan2<<<1, 256, 0, stream>>>(bsum, boff, rowptr, nb, N);
  scan3<<<(N + 255) / 256, 256, 0, stream>>>(rowptr, boff, N);
  fill_csr<<<(E + 255) / 256, 256, 0, stream>>>(src, dst, rowptr, cnt, esrc, E);
  csr_agg<<<(N * 32 + 255) / 256, 256, 0, stream>>>(esrc, rowptr, h16, dis, root, out, N);
}

// Round 5
// 125.039 us; speedup vs baseline: 9.1360x; 1.0203x over previous
//
#include <hip/hip_runtime.h>

#define DD 128

typedef _Float16 h8 __attribute__((ext_vector_type(8)));
typedef _Float16 h4v __attribute__((ext_vector_type(4)));
typedef float f4 __attribute__((ext_vector_type(4)));

// Fused prep: W (fp32) -> Wh (fp16), and zero the degree counters.
// Replaces hipMemsetAsync whose rocclr fill kernel cost ~42 us/replay.
__global__ __launch_bounds__(256) void prep(const float* __restrict__ W,
    _Float16* __restrict__ Wh, int* __restrict__ cnt, int N) {
  const int gid = blockIdx.x * blockDim.x + threadIdx.x;
  const int stride = gridDim.x * blockDim.x;
  for (int i = gid; i < DD * DD; i += stride) Wh[i] = (_Float16)W[i];
  for (int i = gid; i < N; i += stride) cnt[i] = 0;
}

// h16 = fp16(x @ W.T + b) via 16x16x32 f16 MFMA; whole W in wave registers, no LDS.
__global__ __launch_bounds__(256, 2) void gemm_mfma(const float* __restrict__ x,
    const _Float16* __restrict__ Wh, const float* __restrict__ bias,
    _Float16* __restrict__ h16, int nrt) {
  const int lane = threadIdx.x & 63;
  const int wid  = blockIdx.x * 4 + (threadIdx.x >> 6);
  const int nw   = gridDim.x * 4;
  const int lrow = lane & 15;          // A row / B col / C col
  const int lk   = (lane >> 4) << 3;   // k base within 32-wide k-step
  h8 wb[8][4];
#pragma unroll
  for (int jt = 0; jt < 8; ++jt)
#pragma unroll
    for (int ks = 0; ks < 4; ++ks)
      wb[jt][ks] = *(const h8*)(Wh + (jt * 16 + lrow) * DD + ks * 32 + lk);
  float bj[8];
#pragma unroll
  for (int jt = 0; jt < 8; ++jt) bj[jt] = bias[jt * 16 + lrow];
  const int srow = (lane >> 4) << 2;   // C row base = (lane>>4)*4 + reg
  for (int rt = wid; rt < nrt; rt += nw) {
    const int row0 = rt * 16;
    f4 acc[8];
#pragma unroll
    for (int jt = 0; jt < 8; ++jt) acc[jt] = (f4){0.f, 0.f, 0.f, 0.f};
#pragma unroll
    for (int ks = 0; ks < 4; ++ks) {
      const float* ap = x + (size_t)(row0 + lrow) * DD + ks * 32 + lk;
      const f4 a0 = *(const f4*)ap;
      const f4 a1 = *(const f4*)(ap + 4);
      h8 af;
      af[0] = (_Float16)a0.x; af[1] = (_Float16)a0.y;
      af[2] = (_Float16)a0.z; af[3] = (_Float16)a0.w;
      af[4] = (_Float16)a1.x; af[5] = (_Float16)a1.y;
      af[6] = (_Float16)a1.z; af[7] = (_Float16)a1.w;
#pragma unroll
      for (int jt = 0; jt < 8; ++jt)
        acc[jt] = __builtin_amdgcn_mfma_f32_16x16x32_f16(af, wb[jt][ks], acc[jt], 0, 0, 0);
    }
    _Float16* hp = h16 + (size_t)(row0 + srow) * DD + lrow;
#pragma unroll
    for (int jt = 0; jt < 8; ++jt)
#pragma unroll
      for (int r = 0; r < 4; ++r)
        hp[(size_t)r * DD + jt * 16] = (_Float16)(acc[jt][r] + bj[jt]);
  }
}

__global__ void count_deg(const int* __restrict__ dst, int* __restrict__ cnt, int E) {
  int i = blockIdx.x * blockDim.x + threadIdx.x;
  if (i < E) atomicAdd(cnt + dst[i], 1);
}

// two-level exclusive scan; scan1 also emits dis[i] = rsqrt(cnt[i]+1)
__global__ __launch_bounds__(256) void scan1(const int* __restrict__ cnt,
    int* __restrict__ rowptr, int* __restrict__ bsum, float* __restrict__ dis, int N) {
  __shared__ int s[256];
  const int tid = threadIdx.x;
  const int idx = blockIdx.x * 1024 + tid * 4;
  int4 v = {0, 0, 0, 0};
  if (idx + 3 < N) v = *(const int4*)(cnt + idx);
  else {
    if (idx + 0 < N) v.x = cnt[idx];
    if (idx + 1 < N) v.y = cnt[idx + 1];
    if (idx + 2 < N) v.z = cnt[idx + 2];
  }
  if (idx + 0 < N) dis[idx + 0] = rsqrtf((float)(v.x + 1));
  if (idx + 1 < N) dis[idx + 1] = rsqrtf((float)(v.y + 1));
  if (idx + 2 < N) dis[idx + 2] = rsqrtf((float)(v.z + 1));
  if (idx + 3 < N) dis[idx + 3] = rsqrtf((float)(v.w + 1));
  const int mysum = v.x + v.y + v.z + v.w;
  s[tid] = mysum;
  __syncthreads();
  for (int off = 1; off < 256; off <<= 1) {
    int t = (tid >= off) ? s[tid - off] : 0;
    __syncthreads();
    s[tid] += t;
    __syncthreads();
  }
  if (tid == 255) bsum[blockIdx.x] = s[255];
  int p = s[tid] - mysum;
  if (idx + 0 < N) rowptr[idx + 0] = p; p += v.x;
  if (idx + 1 < N) rowptr[idx + 1] = p; p += v.y;
  if (idx + 2 < N) rowptr[idx + 2] = p; p += v.z;
  if (idx + 3 < N) rowptr[idx + 3] = p;
}

__global__ __launch_bounds__(256) void scan2(const int* __restrict__ bsum,
    int* __restrict__ boff, int* __restrict__ rowptr, int nb, int N) {
  __shared__ int s[256];
  const int tid = threadIdx.x;
  const int v = (tid < nb) ? bsum[tid] : 0;
  s[tid] = v;
  __syncthreads();
  for (int off = 1; off < 256; off <<= 1) {
    int t = (tid >= off) ? s[tid - off] : 0;
    __syncthreads();
    s[tid] += t;
    __syncthreads();
  }
  if (tid < nb) boff[tid] = s[tid] - v;
  if (tid == 255) rowptr[N] = s[255];
}

__global__ void scan3(int* __restrict__ rowptr, const int* __restrict__ boff, int N) {
  int i = blockIdx.x * blockDim.x + threadIdx.x;
  if (i < N) rowptr[i] += boff[i >> 10];
}

// scatter edges into dst-grouped order; cnt doubles as a decrementing cursor
// (slots deg-1..0 — any in-bucket permutation is fine; cnt ends at 0).
__global__ void fill_csr(const int* __restrict__ src, const int* __restrict__ dst,
    const int* __restrict__ rowptr, int* __restrict__ cnt,
    int* __restrict__ esrc, int E) {
  int e = blockIdx.x * blockDim.x + threadIdx.x;
  if (e < E) {
    const int t = dst[e];
    const int p = rowptr[t] + atomicAdd(cnt + t, -1) - 1;
    esrc[p] = src[e];
  }
}

// per node: 32 threads each own 4 columns (8B fp16 gather); unroll-2 edge loop.
// out[n] = relu(h16[n]+root)/deg + dis[n] * sum_e relu(h16[src_e])*dis[src_e]
__global__ __launch_bounds__(256) void csr_agg(const int* __restrict__ esrc,
    const int* __restrict__ rowptr, const _Float16* __restrict__ h16,
    const float* __restrict__ dis, const float* __restrict__ root,
    float* __restrict__ out, int N) {
  int gid = blockIdx.x * blockDim.x + threadIdx.x;
  if (gid >= N * 32) return;
  const int n = gid >> 5, q = gid & 31;
  const float dt  = dis[n];
  const float inv = dt * dt;            // 1/deg
  const h4v* hv4 = reinterpret_cast<const h4v*>(h16);
  const float4 rv = reinterpret_cast<const float4*>(root)[q];
  const h4v hv = hv4[n * 32 + q];
  float4 acc;
  acc.x = fmaxf((float)hv[0] + rv.x, 0.0f) * inv;
  acc.y = fmaxf((float)hv[1] + rv.y, 0.0f) * inv;
  acc.z = fmaxf((float)hv[2] + rv.z, 0.0f) * inv;
  acc.w = fmaxf((float)hv[3] + rv.w, 0.0f) * inv;
  float4 ea = {0.f, 0.f, 0.f, 0.f};
  const int beg = rowptr[n], end = rowptr[n + 1];
  int k = beg;
  for (; k + 1 < end; k += 2) {
    const int s0 = esrc[k], s1 = esrc[k + 1];
    const float w0 = dis[s0], w1 = dis[s1];
    const h4v g0 = hv4[s0 * 32 + q];
    const h4v g1 = hv4[s1 * 32 + q];
    ea.x += fmaxf((float)g0[0], 0.0f) * w0;
    ea.y += fmaxf((float)g0[1], 0.0f) * w0;
    ea.z += fmaxf((float)g0[2], 0.0f) * w0;
    ea.w += fmaxf((float)g0[3], 0.0f) * w0;
    ea.x += fmaxf((float)g1[0], 0.0f) * w1;
    ea.y += fmaxf((float)g1[1], 0.0f) * w1;
    ea.z += fmaxf((float)g1[2], 0.0f) * w1;
    ea.w += fmaxf((float)g1[3], 0.0f) * w1;
  }
  if (k < end) {
    const int s0 = esrc[k];
    const float w0 = dis[s0];
    const h4v g0 = hv4[s0 * 32 + q];
    ea.x += fmaxf((float)g0[0], 0.0f) * w0;
    ea.y += fmaxf((float)g0[1], 0.0f) * w0;
    ea.z += fmaxf((float)g0[2], 0.0f) * w0;
    ea.w += fmaxf((float)g0[3], 0.0f) * w0;
  }
  acc.x += ea.x * dt;
  acc.y += ea.y * dt;
  acc.z += ea.z * dt;
  acc.w += ea.w * dt;
  reinterpret_cast<float4*>(out)[gid] = acc;
}

extern "C" void kernel_launch(void* const* d_in, const int* in_sizes, int n_in,
                              void* d_out, int out_size, void* d_ws, size_t ws_size,
                              hipStream_t stream) {
  const float* x    = (const float*)d_in[0];
  const int*   src  = (const int*)d_in[1];
  const int*   dst  = (const int*)d_in[2];
  const float* W    = (const float*)d_in[3];
  const float* bias = (const float*)d_in[4];
  const float* root = (const float*)d_in[5];
  float* out = (float*)d_out;
  const int N = in_sizes[0] / DD;
  const int E = in_sizes[1];

  char* ws = (char*)d_ws;
  size_t off = 0;
  _Float16* h16 = (_Float16*)(ws + off); off += (size_t)N * DD * 2;
  int*   cnt    = (int*)  (ws + off); off += (size_t)N * 4;
  float* dis    = (float*)(ws + off); off += (size_t)N * 4;
  int*   rowptr = (int*)  (ws + off); off += (size_t)(N + 2) * 4;
  int*   esrc   = (int*)  (ws + off); off += (size_t)E * 4;
  int*   bsum   = (int*)  (ws + off); off += 256 * 4;
  int*   boff   = (int*)  (ws + off); off += 256 * 4;
  _Float16* Wh  = (_Float16*)(ws + off); off += (size_t)DD * DD * 2;

  const int nb = (N + 1023) / 1024;  // 49
  prep<<<256, 256, 0, stream>>>(W, Wh, cnt, N);
  gemm_mfma<<<391, 256, 0, stream>>>(x, Wh, bias, h16, N / 16);
  count_deg<<<(E + 255) / 256, 256, 0, stream>>>(dst, cnt, E);
  scan1<<<nb, 256, 0, stream>>>(cnt, rowptr, bsum, dis, N);
  scan2<<<1, 256, 0, stream>>>(bsum, boff, rowptr, nb, N);
  scan3<<<(N + 255) / 256, 256, 0, stream>>>(rowptr, boff, N);
  fill_csr<<<(E + 255) / 256, 256, 0, stream>>>(src, dst, rowptr, cnt, esrc, E);
  csr_agg<<<(N * 32 + 255) / 256, 256, 0, stream>>>(esrc, rowptr, h16, dis, root, out, N);
}